// Round 7
// baseline (2547.499 us; speedup 1.0000x reference)
//
#include <hip/hip_runtime.h>
#include <hip/hip_bf16.h>
#include <cstdint>
#include <cstddef>

// ---------------------------------------------------------------------------
// RANNet: 2-layer recurrent additive network, B=128 S=2048 D=H=256, fc head.
// Round 9 (= round 8 with ext-vector nontemporal store fix).
// Attack the mega-vs-standalone rec slowdown (2060 vs 975 cy/step):
//  - preact prefetch depth 2 -> 4: 8 statically-named register buffers,
//    loop unrolled x8 (T_c divisible by 8).
//  - preP is stream-once data: non-temporal stores in gemm epilogue and
//    non-temporal loads in rec, so the 200MB/tick stream doesn't evict the
//    L2-resident reuse sets (U, W, xa/h1b tiles).
// Topology: blk 0-31 rec0(k) | 32-63 rec1(k-2) | 64-223 gemm (grid-stride).
// 84 KB LDS pad keeps 1 block/CU so gemm can't co-schedule with rec.
// ---------------------------------------------------------------------------

typedef __bf16 bf16;
typedef __bf16 bf16x8 __attribute__((ext_vector_type(8)));
typedef __bf16 bf16x4 __attribute__((ext_vector_type(4)));
typedef __bf16 bf16x2 __attribute__((ext_vector_type(2)));
typedef float  floatx4 __attribute__((ext_vector_type(4)));

#define B_   128
#define S_   2048
#define H_   256
#define NEG_LOG2E -1.442695040888963f
#define NGB  160                 // gemm worker blocks in mega
#define SMEM_BYTES (84 * 1024)   // > 160KiB/2 -> guarantees 1 block per CU

// ---------------------------------------------------------------------------
// Weight prep: concat + fp32->bf16 ( W*cat rows = [Wf;Wi;Wx], U*cat = [Uf;Ui] )
// fcWT = transpose(fcW) kept fp32 for the epilogue.
// ---------------------------------------------------------------------------
__global__ void prep_weights(
    const float* __restrict__ Wf0, const float* __restrict__ Wi0, const float* __restrict__ Wx0,
    const float* __restrict__ Wf1, const float* __restrict__ Wi1, const float* __restrict__ Wx1,
    const float* __restrict__ Uf0, const float* __restrict__ Ui0,
    const float* __restrict__ Uf1, const float* __restrict__ Ui1,
    const float* __restrict__ bf0, const float* __restrict__ bi0, const float* __restrict__ bx0,
    const float* __restrict__ bf1, const float* __restrict__ bi1, const float* __restrict__ bx1,
    const float* __restrict__ fcW,
    bf16* __restrict__ W0cat, bf16* __restrict__ W1cat,
    bf16* __restrict__ U0cat, bf16* __restrict__ U1cat,
    float* __restrict__ b0cat, float* __restrict__ b1cat, float* __restrict__ fcWT)
{
    int tid = blockIdx.x * blockDim.x + threadIdx.x;
    int nth = gridDim.x * blockDim.x;
    for (int idx = tid; idx < 768 * 256; idx += nth) {
        int r = idx >> 8, k = idx & 255, rr = r & 255;
        const float* s0 = (r < 256) ? Wf0 : ((r < 512) ? Wi0 : Wx0);
        const float* s1 = (r < 256) ? Wf1 : ((r < 512) ? Wi1 : Wx1);
        W0cat[idx] = (bf16)s0[rr * 256 + k];
        W1cat[idx] = (bf16)s1[rr * 256 + k];
    }
    for (int idx = tid; idx < 512 * 256; idx += nth) {
        int r = idx >> 8, k = idx & 255, rr = r & 255;
        U0cat[idx] = (bf16)((r < 256 ? Uf0 : Ui0)[rr * 256 + k]);
        U1cat[idx] = (bf16)((r < 256 ? Uf1 : Ui1)[rr * 256 + k]);
    }
    for (int idx = tid; idx < 768; idx += nth) {
        const float* s0 = (idx < 256) ? bf0 : ((idx < 512) ? bi0 : bx0);
        const float* s1 = (idx < 256) ? bf1 : ((idx < 512) ? bi1 : bx1);
        b0cat[idx] = s0[idx & 255];
        b1cat[idx] = s1[idx & 255];
    }
    for (int idx = tid; idx < 256 * 256; idx += nth) {
        int h = idx >> 8, o = idx & 255;
        fcWT[idx] = fcW[o * 256 + h];   // fcWT[h][o]
    }
}

// ---------------------------------------------------------------------------
// x (fp32, [B][S][D]) -> xa (bf16, [S][B][D])  (full sequence, one launch)
// ---------------------------------------------------------------------------
__global__ void convert_x(const float* __restrict__ x, bf16* __restrict__ xa, int t0, int T)
{
    int tid = blockIdx.x * blockDim.x + threadIdx.x;   // T*128*64 threads
    int d4 = tid & 63;
    int b  = (tid >> 6) & 127;
    int t  = tid >> 13;
    if (t >= T) return;
    const float4* src = (const float4*)(x + ((size_t)b * S_ + t0 + t) * H_) + d4;
    float4 v = *src;
    bf16x4 o = { (bf16)v.x, (bf16)v.y, (bf16)v.z, (bf16)v.w };
    *((bf16x4*)(xa + ((size_t)t * B_ + b) * H_) + d4) = o;
}

// ---------------------------------------------------------------------------
// Device: one 128x128 preact GEMM tile (512 thr, 8 waves, 64x32 per wave).
// C[128 rows][128 of 768 cols] = A[128][256] @ W[768][256]^T + bias, written
// f32 into rec layout preP[(t*32 + (m>>2))*3072 + c*4 + (m&3)];
// f/i (c<512) pre-scaled by -log2(e). Non-temporal floatx4 stores (stream-
// once data; keep it out of the hot L2 sets).
// ---------------------------------------------------------------------------
__device__ __forceinline__ void gemm_tile(
    char* smem,
    const bf16* __restrict__ Abase,   // 128 rows, row stride 256
    const bf16* __restrict__ W, const float* __restrict__ bias,
    float* __restrict__ preP, int t, int nb)
{
    bf16* At = (bf16*)smem;           // [128][32]
    bf16* Bt = (bf16*)smem + 128 * 32;
    int n0 = nb * 128;
    int tid = threadIdx.x;
    int lane = tid & 63, wave = tid >> 6;
    int wm = (wave >> 2) * 64, wn = (wave & 3) * 32;
    int qm = lane & 15, qk = lane >> 4;
    floatx4 acc[4][2] = {};

    for (int k0 = 0; k0 < 256; k0 += 32) {
        {   // stage: 512 threads x one 16B chunk per buffer
            int c = tid, row = c >> 2, kc = c & 3;
            *(bf16x8*)(At + c * 8) = *(const bf16x8*)(Abase + (size_t)row * 256 + k0 + kc * 8);
            *(bf16x8*)(Bt + c * 8) = *(const bf16x8*)(W + (size_t)(n0 + row) * 256 + k0 + kc * 8);
        }
        __syncthreads();
        bf16x8 af[4], bfr[2];
#pragma unroll
        for (int i = 0; i < 4; ++i)
            af[i] = *(const bf16x8*)(At + (wm + i * 16 + qm) * 32 + qk * 8);
#pragma unroll
        for (int n = 0; n < 2; ++n)
            bfr[n] = *(const bf16x8*)(Bt + (wn + n * 16 + qm) * 32 + qk * 8);
#pragma unroll
        for (int mi = 0; mi < 4; ++mi)
#pragma unroll
            for (int ni = 0; ni < 2; ++ni)
                acc[mi][ni] = __builtin_amdgcn_mfma_f32_16x16x32_bf16(af[mi], bfr[ni], acc[mi][ni], 0, 0, 0);
        __syncthreads();
    }
#pragma unroll
    for (int mi = 0; mi < 4; ++mi) {
        int b = wm + mi * 16 + qk * 4;        // + r ; multiple of 4
        int wgi = b >> 2;
#pragma unroll
        for (int ni = 0; ni < 2; ++ni) {
            int c = n0 + wn + ni * 16 + qm;
            int g = c >> 8;
            float bb = bias[c];
            floatx4 v;
#pragma unroll
            for (int r = 0; r < 4; ++r) {
                float val = acc[mi][ni][r] + bb;
                v[r] = (g < 2) ? NEG_LOG2E * val : val;
            }
            __builtin_nontemporal_store(v,
                (floatx4*)(preP + ((size_t)t * 32 + wgi) * 3072 + (size_t)c * 4));
        }
    }
}

// ---------------------------------------------------------------------------
// Device: recurrence for one WG (4 batch rows). 512 thr, 8 waves; wave w owns
// h-cols [32w,32w+32) and computes BOTH f and i gates. M=16 MFMA, A rows read
// as (qm&3) -> C rows replicate mod 4: every lane's 4 acc regs hold
// z[0..3][col=lane&15]; ownership (row=lane>>4, col) is a per-lane 4->1
// register select. One lgkm-only barrier per step.
// Depth-4 prefetch: 8 named buffers of 6 non-temporal dwords, unroll x8.
// ---------------------------------------------------------------------------
__device__ __forceinline__ void rec_wg(
    char* smem, int wg,
    const float* __restrict__ preP,  // [T][32 wg][768 c][4 r] f32
    bf16* __restrict__ hout,         // [T][128][256] bf16, or nullptr
    const bf16* __restrict__ Ucat,   // [512][256] = [Uf;Ui]
    float* __restrict__ hstate,      // [128][256] in/out
    int T)
{
    bf16* hbb = (bf16*)smem;             // [2 bufs][4 rows * 272], 544B row stride
    const int tid = threadIdx.x, lane = tid & 63, wave = tid >> 6;
    const int qm = lane & 15, qk = lane >> 4;
    const int row = qk;                  // 0..3 = output row this lane owns
    const int colq = qm;                 // 0..15
    const int bbase = wg * 4, cb = wave * 32;
    const bool selhi16 = (lane & 16) != 0;   // reg-select masks (hoisted)
    const bool selhi32 = (lane & 32) != 0;

    // stationary U fragments (B-operand layout): row n = col index, k contig
    bf16x8 Ufr[2][8], Uir[2][8];
#pragma unroll
    for (int nt = 0; nt < 2; ++nt)
#pragma unroll
        for (int kt = 0; kt < 8; ++kt) {
            Ufr[nt][kt] = *(const bf16x8*)(Ucat + (size_t)(cb + nt * 16 + qm) * 256 + kt * 32 + qk * 8);
            Uir[nt][kt] = *(const bf16x8*)(Ucat + (size_t)(256 + cb + nt * 16 + qm) * 256 + kt * 32 + qk * 8);
        }
    {   // init LDS h (buf 0) from fp32 state: 4 rows x 256 cols, 2 cols/thread
        int r2 = tid >> 7, c2 = (tid & 127) * 2;
        const float* hs = hstate + (size_t)(bbase + r2) * 256 + c2;
        bf16x2 v = { (bf16)hs[0], (bf16)hs[1] };
        *(bf16x2*)(hbb + r2 * 272 + c2) = v;
    }
    float hm0 = hstate[(size_t)(bbase + row) * 256 + cb + colq];
    float hm1 = hstate[(size_t)(bbase + row) * 256 + cb + 16 + colq];
    __syncthreads();

    // per-lane preact base: idx = t*98304 + wg*3072 + (g*256+cb+nt*16+colq)*4 + row
    const float* pw = preP + (size_t)wg * 3072 + (size_t)((cb + colq) * 4 + row);
#define PLD(dst, tt) { size_t o_ = (size_t)(tt) * 98304;                          \
        dst[0] = __builtin_nontemporal_load(pw + o_);                             \
        dst[1] = __builtin_nontemporal_load(pw + o_ + 64);                        \
        dst[2] = __builtin_nontemporal_load(pw + o_ + 1024);                      \
        dst[3] = __builtin_nontemporal_load(pw + o_ + 1088);                      \
        dst[4] = __builtin_nontemporal_load(pw + o_ + 2048);                      \
        dst[5] = __builtin_nontemporal_load(pw + o_ + 2112); }

    int cur = 0;

    // every lane: reg j = z[row=j][col=lane&15]  ->  pick reg (lane>>4)
    auto spread = [&](floatx4 v) -> float {
        float s01 = selhi16 ? v[1] : v[0];
        float s23 = selhi16 ? v[3] : v[2];
        return selhi32 ? s23 : s01;
    };

    auto step = [&](int t, const float* p) {
        floatx4 f0{}, f1{}, i0{}, i1{};
        const bf16* hc = hbb + cur * (4 * 272);
#pragma unroll
        for (int kt = 0; kt < 8; ++kt) {
            bf16x8 a = *(const bf16x8*)(hc + (qm & 3) * 272 + kt * 32 + qk * 8);
            f0 = __builtin_amdgcn_mfma_f32_16x16x32_bf16(a, Ufr[0][kt], f0, 0, 0, 0);
            f1 = __builtin_amdgcn_mfma_f32_16x16x32_bf16(a, Ufr[1][kt], f1, 0, 0, 0);
            i0 = __builtin_amdgcn_mfma_f32_16x16x32_bf16(a, Uir[0][kt], i0, 0, 0, 0);
            i1 = __builtin_amdgcn_mfma_f32_16x16x32_bf16(a, Uir[1][kt], i1, 0, 0, 0);
        }
        float zf0 = spread(f0), zf1 = spread(f1);
        float zi0 = spread(i0), zi1 = spread(i1);
        bf16* hn = hbb + (cur ^ 1) * (4 * 272);
        {   // nt = 0
            float ef = fminf(fmaf(zf0, NEG_LOG2E, p[0]), 80.0f);
            float ei = fminf(fmaf(zi0, NEG_LOG2E, p[2]), 80.0f);
            float A1 = 1.0f + __builtin_amdgcn_exp2f(ef);
            float B1 = 1.0f + __builtin_amdgcn_exp2f(ei);
            float N  = fmaf(hm0, B1, p[4] * A1);
            hm0 = N * __builtin_amdgcn_rcpf(A1 * B1);
            hn[row * 272 + cb + colq] = (bf16)hm0;
        }
        {   // nt = 1
            float ef = fminf(fmaf(zf1, NEG_LOG2E, p[1]), 80.0f);
            float ei = fminf(fmaf(zi1, NEG_LOG2E, p[3]), 80.0f);
            float A1 = 1.0f + __builtin_amdgcn_exp2f(ef);
            float B1 = 1.0f + __builtin_amdgcn_exp2f(ei);
            float N  = fmaf(hm1, B1, p[5] * A1);
            hm1 = N * __builtin_amdgcn_rcpf(A1 * B1);
            hn[row * 272 + cb + 16 + colq] = (bf16)hm1;
        }
        // LDS-visibility barrier only; global prefetch stays in flight.
        asm volatile("s_waitcnt lgkmcnt(0)\n\ts_barrier" ::: "memory");
        if (hout) {   // coalesced store of h_t from the just-written buffer
            int r2 = tid >> 7, c2 = (tid & 127) * 2;
            bf16x2 v = *(const bf16x2*)(hn + r2 * 272 + c2);
            *(bf16x2*)(hout + ((size_t)t * 128 + bbase + r2) * 256 + c2) = v;
        }
        cur ^= 1;
    };

    // depth-4 prefetch: 8 statically-named buffers, loop unrolled x8
    // (T_c is a power of two >= 32, so T % 8 == 0)
    float bA[6], bB[6], bC[6], bD[6], bE[6], bF[6], bG[6], bH[6];
#define CL(tt) ((tt) < T ? (tt) : T - 1)
    PLD(bA, 0); PLD(bB, CL(1)); PLD(bC, CL(2)); PLD(bD, CL(3));
    for (int t = 0; t < T; t += 8) {
        PLD(bE, CL(t + 4));  step(t,     bA);
        PLD(bF, CL(t + 5));  step(t + 1, bB);
        PLD(bG, CL(t + 6));  step(t + 2, bC);
        PLD(bH, CL(t + 7));  step(t + 3, bD);
        PLD(bA, CL(t + 8));  step(t + 4, bE);
        PLD(bB, CL(t + 9));  step(t + 5, bF);
        PLD(bC, CL(t + 10)); step(t + 6, bG);
        PLD(bD, CL(t + 11)); step(t + 7, bH);
    }
#undef CL
#undef PLD
    hstate[(size_t)(bbase + row) * 256 + cb + colq]      = hm0;
    hstate[(size_t)(bbase + row) * 256 + cb + 16 + colq] = hm1;
}

// ---------------------------------------------------------------------------
// Mega pipeline tick: blocks 0-31 rec0(chunk k), 32-63 rec1(chunk k-2),
// 64..64+NGB-1 grid-stride over gemm0(chunk k+1) + gemm1(chunk k-1) tiles.
// flags: bit0 rec0, bit1 gemm1, bit2 rec1, bit3 gemm0.
// ---------------------------------------------------------------------------
__global__ __launch_bounds__(512) void mega(
    const bf16* __restrict__ xa, int t0n,
    const bf16* __restrict__ W0, const float* __restrict__ b0,
    const bf16* __restrict__ W1, const float* __restrict__ b1,
    const bf16* __restrict__ U0, const bf16* __restrict__ U1,
    float* __restrict__ h0s, float* __restrict__ h1s,
    float* __restrict__ pre0n,        // gemm0 out  (chunk k+1)
    const float* __restrict__ pre0c,  // rec0  in   (chunk k)
    bf16*  __restrict__ h1bc,         // rec0  out  (chunk k)
    const bf16* __restrict__ h1bp,    // gemm1 in   (chunk k-1)
    float* __restrict__ pre1p,        // gemm1 out  (chunk k-1)
    const float* __restrict__ pre1pp, // rec1  in   (chunk k-2)
    int flags, int T)
{
    __shared__ __align__(16) char smem[SMEM_BYTES];
    int bx = blockIdx.x;
    if (bx < 32) {
        if (flags & 1) rec_wg(smem, bx, pre0c, h1bc, U0, h0s, T);
        return;
    }
    if (bx < 64) {
        if (flags & 4) rec_wg(smem, bx - 32, pre1pp, nullptr, U1, h1s, T);
        return;
    }
    int ng0 = (flags & 8) ? T * 6 : 0;
    int ng1 = (flags & 2) ? T * 6 : 0;
    for (int tile = bx - 64; tile < ng0 + ng1; tile += NGB) {
        bool is0 = tile < ng0;
        int tt = is0 ? tile : tile - ng0;
        int t = tt / 6, nb = tt - t * 6;
        const bf16* A = is0 ? (xa + (size_t)(t0n + t) * 32768)
                            : (h1bp + (size_t)t * 32768);
        gemm_tile(smem, A, is0 ? W0 : W1, is0 ? b0 : b1,
                  is0 ? pre0n : pre1p, t, nb);
    }
}

// ---------------------------------------------------------------------------
// fc head: out[b][o] = fcb[o] + sum_h h2[b][h] * fcWT[h][o]   (all fp32)
// ---------------------------------------------------------------------------
__global__ void fc_head(const float* __restrict__ h2, const float* __restrict__ fcWT,
                        const float* __restrict__ fcb, float* __restrict__ out)
{
    int b = blockIdx.x, o = threadIdx.x;
    __shared__ float hrow[256];
    hrow[o] = h2[(size_t)b * 256 + o];
    __syncthreads();
    float acc = fcb[o];
#pragma unroll 8
    for (int h = 0; h < 256; ++h)
        acc = fmaf(hrow[h], fcWT[h * 256 + o], acc);
    out[(size_t)b * 256 + o] = acc;
}

// ---------------------------------------------------------------------------
extern "C" void kernel_launch(void* const* d_in, const int* in_sizes, int n_in,
                              void* d_out, int out_size, void* d_ws, size_t ws_size,
                              hipStream_t stream)
{
    (void)in_sizes; (void)n_in; (void)out_size;
    const float* x   = (const float*)d_in[0];
    const float* Wf0 = (const float*)d_in[1];
    const float* bf0 = (const float*)d_in[2];
    const float* Uf0 = (const float*)d_in[3];
    const float* Wi0 = (const float*)d_in[4];
    const float* bi0 = (const float*)d_in[5];
    const float* Ui0 = (const float*)d_in[6];
    const float* Wx0 = (const float*)d_in[7];
    const float* bx0 = (const float*)d_in[8];
    const float* Wf1 = (const float*)d_in[9];
    const float* bf1 = (const float*)d_in[10];
    const float* Uf1 = (const float*)d_in[11];
    const float* Wi1 = (const float*)d_in[12];
    const float* bi1 = (const float*)d_in[13];
    const float* Ui1 = (const float*)d_in[14];
    const float* Wx1 = (const float*)d_in[15];
    const float* bx1 = (const float*)d_in[16];
    const float* fcW = (const float*)d_in[17];
    const float* fcb = (const float*)d_in[18];

    char* p = (char*)d_ws;
    auto alloc = [&](size_t bytes) -> char* {
        char* r = p; p += (bytes + 255) & ~(size_t)255; return r;
    };
    bf16*  W0cat = (bf16*)alloc(768 * 256 * 2);
    bf16*  W1cat = (bf16*)alloc(768 * 256 * 2);
    bf16*  U0cat = (bf16*)alloc(512 * 256 * 2);
    bf16*  U1cat = (bf16*)alloc(512 * 256 * 2);
    float* b0cat = (float*)alloc(768 * 4);
    float* b1cat = (float*)alloc(768 * 4);
    float* fcWT  = (float*)alloc(256 * 256 * 4);
    float* h0s   = (float*)alloc(128 * 256 * 4);
    float* h1s   = (float*)alloc(128 * 256 * 4);
    size_t fixed = (size_t)(p - (char*)d_ws);

    // need(T_c) = fixed + xa(full S) + 2*pre0 + 2*pre1 + 2*h1b
    int T_c = 128;
    while (T_c > 32 &&
           fixed + 134217728ULL + (size_t)T_c * 1703936ULL + 4096 > ws_size)
        T_c >>= 1;
    bf16*  xa    = (bf16*)alloc((size_t)S_ * 128 * 256 * 2);
    float* pre0s[2], *pre1s[2];
    bf16*  h1bs[2];
    pre0s[0] = (float*)alloc((size_t)T_c * 128 * 768 * 4);
    pre0s[1] = (float*)alloc((size_t)T_c * 128 * 768 * 4);
    pre1s[0] = (float*)alloc((size_t)T_c * 128 * 768 * 4);
    pre1s[1] = (float*)alloc((size_t)T_c * 128 * 768 * 4);
    h1bs[0]  = (bf16*)alloc((size_t)T_c * 128 * 256 * 2);
    h1bs[1]  = (bf16*)alloc((size_t)T_c * 128 * 256 * 2);

    hipMemsetAsync(h0s, 0, 128 * 256 * 4, stream);
    hipMemsetAsync(h1s, 0, 128 * 256 * 4, stream);

    prep_weights<<<512, 256, 0, stream>>>(Wf0, Wi0, Wx0, Wf1, Wi1, Wx1,
                                          Uf0, Ui0, Uf1, Ui1,
                                          bf0, bi0, bx0, bf1, bi1, bx1, fcW,
                                          W0cat, W1cat, U0cat, U1cat, b0cat, b1cat, fcWT);
    convert_x<<<S_ * 32, 256, 0, stream>>>(x, xa, 0, S_);

    int NC = S_ / T_c;
    for (int k = -1; k <= NC + 1; ++k) {
        int flags = 0;
        if (k >= 0 && k < NC)     flags |= 1;   // rec0 chunk k
        if (k >= 1 && k <= NC)    flags |= 2;   // gemm1 chunk k-1
        if (k >= 2 && k <= NC+1)  flags |= 4;   // rec1 chunk k-2
        if (k <= NC - 2)          flags |= 8;   // gemm0 chunk k+1
        mega<<<64 + NGB, 512, 0, stream>>>(
            xa, (k + 1) * T_c,
            W0cat, b0cat, W1cat, b1cat, U0cat, U1cat, h0s, h1s,
            pre0s[(k + 1) & 1],   // gemm0 out
            pre0s[k & 1],         // rec0 in
            h1bs[k & 1],          // rec0 out
            h1bs[(k - 1) & 1],    // gemm1 in
            pre1s[(k - 1) & 1],   // gemm1 out
            pre1s[k & 1],         // rec1 in  ((k-2)&1 == k&1)
            flags, T_c);
    }
    fc_head<<<128, 256, 0, stream>>>(h1s, fcWT, fcb, (float*)d_out);
}

// Round 8
// 2468.341 us; speedup vs baseline: 1.0321x; 1.0321x over previous
//
#include <hip/hip_runtime.h>
#include <hip/hip_bf16.h>
#include <cstdint>
#include <cstddef>

// ---------------------------------------------------------------------------
// RANNet: 2-layer recurrent additive network, B=128 S=2048 D=H=256, fc head.
// Round 10: overlap the rec epilogue with the MFMA pipe drain.
// Step model (round-3/7 data): 1947 cy = 1242 cy MFMA pipe + ~700 cy tail.
// The tail exists because all 4 accumulator chains interleave per-kt, so the
// epilogue waits for MFMA #29-31 of 32. New order: nt=0 chains (f0,i0) fully
// first (A-frags stashed in 32 VGPRs), nt=1 chains second, epilogue-0 placed
// between -> its VALU overlaps the nt=1 pipe drain. hout stores come from own
// registers pre-barrier (no post-barrier LDS read).
// Reverts round-7 regressions: plain loads/stores (preP is L3-resident at
// T_c=128; nt hints forced HBM), depth-2 prefetch, 32/32/160 topology.
// ---------------------------------------------------------------------------

typedef __bf16 bf16;
typedef __bf16 bf16x8 __attribute__((ext_vector_type(8)));
typedef __bf16 bf16x4 __attribute__((ext_vector_type(4)));
typedef __bf16 bf16x2 __attribute__((ext_vector_type(2)));
typedef float  floatx4 __attribute__((ext_vector_type(4)));

#define B_   128
#define S_   2048
#define H_   256
#define NEG_LOG2E -1.442695040888963f
#define NGB  160                 // gemm worker blocks in mega
#define SMEM_BYTES (84 * 1024)   // > 160KiB/2 -> guarantees 1 block per CU

// ---------------------------------------------------------------------------
// Weight prep: concat + fp32->bf16 ( W*cat rows = [Wf;Wi;Wx], U*cat = [Uf;Ui] )
// fcWT = transpose(fcW) kept fp32 for the epilogue.
// ---------------------------------------------------------------------------
__global__ void prep_weights(
    const float* __restrict__ Wf0, const float* __restrict__ Wi0, const float* __restrict__ Wx0,
    const float* __restrict__ Wf1, const float* __restrict__ Wi1, const float* __restrict__ Wx1,
    const float* __restrict__ Uf0, const float* __restrict__ Ui0,
    const float* __restrict__ Uf1, const float* __restrict__ Ui1,
    const float* __restrict__ bf0, const float* __restrict__ bi0, const float* __restrict__ bx0,
    const float* __restrict__ bf1, const float* __restrict__ bi1, const float* __restrict__ bx1,
    const float* __restrict__ fcW,
    bf16* __restrict__ W0cat, bf16* __restrict__ W1cat,
    bf16* __restrict__ U0cat, bf16* __restrict__ U1cat,
    float* __restrict__ b0cat, float* __restrict__ b1cat, float* __restrict__ fcWT)
{
    int tid = blockIdx.x * blockDim.x + threadIdx.x;
    int nth = gridDim.x * blockDim.x;
    for (int idx = tid; idx < 768 * 256; idx += nth) {
        int r = idx >> 8, k = idx & 255, rr = r & 255;
        const float* s0 = (r < 256) ? Wf0 : ((r < 512) ? Wi0 : Wx0);
        const float* s1 = (r < 256) ? Wf1 : ((r < 512) ? Wi1 : Wx1);
        W0cat[idx] = (bf16)s0[rr * 256 + k];
        W1cat[idx] = (bf16)s1[rr * 256 + k];
    }
    for (int idx = tid; idx < 512 * 256; idx += nth) {
        int r = idx >> 8, k = idx & 255, rr = r & 255;
        U0cat[idx] = (bf16)((r < 256 ? Uf0 : Ui0)[rr * 256 + k]);
        U1cat[idx] = (bf16)((r < 256 ? Uf1 : Ui1)[rr * 256 + k]);
    }
    for (int idx = tid; idx < 768; idx += nth) {
        const float* s0 = (idx < 256) ? bf0 : ((idx < 512) ? bi0 : bx0);
        const float* s1 = (idx < 256) ? bf1 : ((idx < 512) ? bi1 : bx1);
        b0cat[idx] = s0[idx & 255];
        b1cat[idx] = s1[idx & 255];
    }
    for (int idx = tid; idx < 256 * 256; idx += nth) {
        int h = idx >> 8, o = idx & 255;
        fcWT[idx] = fcW[o * 256 + h];   // fcWT[h][o]
    }
}

// ---------------------------------------------------------------------------
// x (fp32, [B][S][D]) -> xa (bf16, [S][B][D])  (full sequence, one launch)
// ---------------------------------------------------------------------------
__global__ void convert_x(const float* __restrict__ x, bf16* __restrict__ xa, int t0, int T)
{
    int tid = blockIdx.x * blockDim.x + threadIdx.x;   // T*128*64 threads
    int d4 = tid & 63;
    int b  = (tid >> 6) & 127;
    int t  = tid >> 13;
    if (t >= T) return;
    const float4* src = (const float4*)(x + ((size_t)b * S_ + t0 + t) * H_) + d4;
    float4 v = *src;
    bf16x4 o = { (bf16)v.x, (bf16)v.y, (bf16)v.z, (bf16)v.w };
    *((bf16x4*)(xa + ((size_t)t * B_ + b) * H_) + d4) = o;
}

// ---------------------------------------------------------------------------
// Device: one 128x128 preact GEMM tile (512 thr, 8 waves, 64x32 per wave).
// C[128 rows][128 of 768 cols] = A[128][256] @ W[768][256]^T + bias, written
// f32 into rec layout preP[(t*32 + (m>>2))*3072 + c*4 + (m&3)];
// f/i (c<512) pre-scaled by -log2(e). Coalesced 16B stores.
// ---------------------------------------------------------------------------
__device__ __forceinline__ void gemm_tile(
    char* smem,
    const bf16* __restrict__ Abase,   // 128 rows, row stride 256
    const bf16* __restrict__ W, const float* __restrict__ bias,
    float* __restrict__ preP, int t, int nb)
{
    bf16* At = (bf16*)smem;           // [128][32]
    bf16* Bt = (bf16*)smem + 128 * 32;
    int n0 = nb * 128;
    int tid = threadIdx.x;
    int lane = tid & 63, wave = tid >> 6;
    int wm = (wave >> 2) * 64, wn = (wave & 3) * 32;
    int qm = lane & 15, qk = lane >> 4;
    floatx4 acc[4][2] = {};

    for (int k0 = 0; k0 < 256; k0 += 32) {
        {   // stage: 512 threads x one 16B chunk per buffer
            int c = tid, row = c >> 2, kc = c & 3;
            *(bf16x8*)(At + c * 8) = *(const bf16x8*)(Abase + (size_t)row * 256 + k0 + kc * 8);
            *(bf16x8*)(Bt + c * 8) = *(const bf16x8*)(W + (size_t)(n0 + row) * 256 + k0 + kc * 8);
        }
        __syncthreads();
        bf16x8 af[4], bfr[2];
#pragma unroll
        for (int i = 0; i < 4; ++i)
            af[i] = *(const bf16x8*)(At + (wm + i * 16 + qm) * 32 + qk * 8);
#pragma unroll
        for (int n = 0; n < 2; ++n)
            bfr[n] = *(const bf16x8*)(Bt + (wn + n * 16 + qm) * 32 + qk * 8);
#pragma unroll
        for (int mi = 0; mi < 4; ++mi)
#pragma unroll
            for (int ni = 0; ni < 2; ++ni)
                acc[mi][ni] = __builtin_amdgcn_mfma_f32_16x16x32_bf16(af[mi], bfr[ni], acc[mi][ni], 0, 0, 0);
        __syncthreads();
    }
#pragma unroll
    for (int mi = 0; mi < 4; ++mi) {
        int b = wm + mi * 16 + qk * 4;        // + r ; multiple of 4
        int wgi = b >> 2;
#pragma unroll
        for (int ni = 0; ni < 2; ++ni) {
            int c = n0 + wn + ni * 16 + qm;
            int g = c >> 8;
            float bb = bias[c];
            floatx4 v;
#pragma unroll
            for (int r = 0; r < 4; ++r) {
                float val = acc[mi][ni][r] + bb;
                v[r] = (g < 2) ? NEG_LOG2E * val : val;
            }
            *(floatx4*)(preP + ((size_t)t * 32 + wgi) * 3072 + (size_t)c * 4) = v;
        }
    }
}

// ---------------------------------------------------------------------------
// Device: recurrence for one WG (4 batch rows). 512 thr, 8 waves; wave w owns
// h-cols [32w,32w+32), both gates. M=16 MFMA, A rows read as (qm&3) -> C rows
// replicate mod 4: every lane's 4 acc regs hold z[0..3][col=lane&15];
// ownership (row=lane>>4, col) is a per-lane 4->1 register select.
// Split-phase step: nt=0 chains first (A-frags stashed), nt=1 chains second,
// epilogue-0 between (overlaps pipe drain). Own-register hout stores.
// One lgkm-only barrier per step; depth-2 prefetch of 6 dwords/lane/step.
// ---------------------------------------------------------------------------
__device__ __forceinline__ void rec_wg(
    char* smem, int wg,
    const float* __restrict__ preP,  // [T][32 wg][768 c][4 r] f32
    bf16* __restrict__ hout,         // [T][128][256] bf16, or nullptr
    const bf16* __restrict__ Ucat,   // [512][256] = [Uf;Ui]
    float* __restrict__ hstate,      // [128][256] in/out
    int T)
{
    bf16* hbb = (bf16*)smem;             // [2 bufs][4 rows * 272], 544B row stride
    const int tid = threadIdx.x, lane = tid & 63, wave = tid >> 6;
    const int qm = lane & 15, qk = lane >> 4;
    const int row = qk;                  // 0..3 = output row this lane owns
    const int colq = qm;                 // 0..15
    const int bbase = wg * 4, cb = wave * 32;
    const bool selhi16 = (lane & 16) != 0;   // reg-select masks (hoisted)
    const bool selhi32 = (lane & 32) != 0;

    // stationary U fragments (B-operand layout): row n = col index, k contig
    bf16x8 Ufr[2][8], Uir[2][8];
#pragma unroll
    for (int nt = 0; nt < 2; ++nt)
#pragma unroll
        for (int kt = 0; kt < 8; ++kt) {
            Ufr[nt][kt] = *(const bf16x8*)(Ucat + (size_t)(cb + nt * 16 + qm) * 256 + kt * 32 + qk * 8);
            Uir[nt][kt] = *(const bf16x8*)(Ucat + (size_t)(256 + cb + nt * 16 + qm) * 256 + kt * 32 + qk * 8);
        }
    {   // init LDS h (buf 0) from fp32 state: 4 rows x 256 cols, 2 cols/thread
        int r2 = tid >> 7, c2 = (tid & 127) * 2;
        const float* hs = hstate + (size_t)(bbase + r2) * 256 + c2;
        bf16x2 v = { (bf16)hs[0], (bf16)hs[1] };
        *(bf16x2*)(hbb + r2 * 272 + c2) = v;
    }
    float hm0 = hstate[(size_t)(bbase + row) * 256 + cb + colq];
    float hm1 = hstate[(size_t)(bbase + row) * 256 + cb + 16 + colq];
    __syncthreads();

    // per-lane preact base: idx = t*98304 + wg*3072 + (g*256+cb+nt*16+colq)*4 + row
    const float* pw = preP + (size_t)wg * 3072 + (size_t)((cb + colq) * 4 + row);
#define PLD(dst, tt) { size_t o_ = (size_t)(tt) * 98304;                          \
        dst[0] = pw[o_];        dst[1] = pw[o_ + 64];   dst[2] = pw[o_ + 1024];   \
        dst[3] = pw[o_ + 1088]; dst[4] = pw[o_ + 2048]; dst[5] = pw[o_ + 2112]; }

    int cur = 0;

    // every lane: reg j = z[row=j][col=lane&15]  ->  pick reg (lane>>4)
    auto spread = [&](floatx4 v) -> float {
        float s01 = selhi16 ? v[1] : v[0];
        float s23 = selhi16 ? v[3] : v[2];
        return selhi32 ? s23 : s01;
    };

    auto step = [&](int t, const float* p) {
        const bf16* hc = hbb + cur * (4 * 272);
        bf16* hn = hbb + (cur ^ 1) * (4 * 272);
        floatx4 f0{}, i0{}, f1{}, i1{};
        bf16x8 a0, a1, a2, a3, a4, a5, a6, a7;
        // phase 1: load A-frags, run nt=0 chains (f0, i0) to completion first
        a0 = *(const bf16x8*)(hc + (qm & 3) * 272 + 0 * 32 + qk * 8);
        a1 = *(const bf16x8*)(hc + (qm & 3) * 272 + 1 * 32 + qk * 8);
        a2 = *(const bf16x8*)(hc + (qm & 3) * 272 + 2 * 32 + qk * 8);
        a3 = *(const bf16x8*)(hc + (qm & 3) * 272 + 3 * 32 + qk * 8);
        a4 = *(const bf16x8*)(hc + (qm & 3) * 272 + 4 * 32 + qk * 8);
        a5 = *(const bf16x8*)(hc + (qm & 3) * 272 + 5 * 32 + qk * 8);
        a6 = *(const bf16x8*)(hc + (qm & 3) * 272 + 6 * 32 + qk * 8);
        a7 = *(const bf16x8*)(hc + (qm & 3) * 272 + 7 * 32 + qk * 8);
#define MF(acc, a, u) acc = __builtin_amdgcn_mfma_f32_16x16x32_bf16(a, u, acc, 0, 0, 0)
        MF(f0, a0, Ufr[0][0]); MF(i0, a0, Uir[0][0]);
        MF(f0, a1, Ufr[0][1]); MF(i0, a1, Uir[0][1]);
        MF(f0, a2, Ufr[0][2]); MF(i0, a2, Uir[0][2]);
        MF(f0, a3, Ufr[0][3]); MF(i0, a3, Uir[0][3]);
        MF(f0, a4, Ufr[0][4]); MF(i0, a4, Uir[0][4]);
        MF(f0, a5, Ufr[0][5]); MF(i0, a5, Uir[0][5]);
        MF(f0, a6, Ufr[0][6]); MF(i0, a6, Uir[0][6]);
        MF(f0, a7, Ufr[0][7]); MF(i0, a7, Uir[0][7]);
        // phase 2: nt=1 chains (issue while epilogue-0 runs on the VALU)
        MF(f1, a0, Ufr[1][0]); MF(i1, a0, Uir[1][0]);
        MF(f1, a1, Ufr[1][1]); MF(i1, a1, Uir[1][1]);
        MF(f1, a2, Ufr[1][2]); MF(i1, a2, Uir[1][2]);
        MF(f1, a3, Ufr[1][3]); MF(i1, a3, Uir[1][3]);
        MF(f1, a4, Ufr[1][4]); MF(i1, a4, Uir[1][4]);
        MF(f1, a5, Ufr[1][5]); MF(i1, a5, Uir[1][5]);
        MF(f1, a6, Ufr[1][6]); MF(i1, a6, Uir[1][6]);
        MF(f1, a7, Ufr[1][7]); MF(i1, a7, Uir[1][7]);
#undef MF
        // epilogue nt=0: depends only on f0/i0 (done early) -> overlaps drain
        {
            float zf0 = spread(f0), zi0 = spread(i0);
            float ef = fminf(fmaf(zf0, NEG_LOG2E, p[0]), 80.0f);
            float ei = fminf(fmaf(zi0, NEG_LOG2E, p[2]), 80.0f);
            float A1 = 1.0f + __builtin_amdgcn_exp2f(ef);
            float B1 = 1.0f + __builtin_amdgcn_exp2f(ei);
            float N  = fmaf(hm0, B1, p[4] * A1);
            hm0 = N * __builtin_amdgcn_rcpf(A1 * B1);
            hn[row * 272 + cb + colq] = (bf16)hm0;
            if (hout)   // own-register store, pre-barrier, fire-and-forget
                hout[((size_t)t * 128 + bbase + row) * 256 + cb + colq] = (bf16)hm0;
        }
        // epilogue nt=1
        {
            float zf1 = spread(f1), zi1 = spread(i1);
            float ef = fminf(fmaf(zf1, NEG_LOG2E, p[1]), 80.0f);
            float ei = fminf(fmaf(zi1, NEG_LOG2E, p[3]), 80.0f);
            float A1 = 1.0f + __builtin_amdgcn_exp2f(ef);
            float B1 = 1.0f + __builtin_amdgcn_exp2f(ei);
            float N  = fmaf(hm1, B1, p[5] * A1);
            hm1 = N * __builtin_amdgcn_rcpf(A1 * B1);
            hn[row * 272 + cb + 16 + colq] = (bf16)hm1;
            if (hout)
                hout[((size_t)t * 128 + bbase + row) * 256 + cb + 16 + colq] = (bf16)hm1;
        }
        // LDS-visibility barrier only; global traffic stays in flight.
        asm volatile("s_waitcnt lgkmcnt(0)\n\ts_barrier" ::: "memory");
        cur ^= 1;
    };

    // depth-2 prefetch, 4 statically-named buffers, loop unrolled x4
    float bA[6], bB[6], bC[6], bD[6];
    PLD(bA, 0);
    PLD(bB, 1);
    for (int t = 0; t < T; t += 4) {
        PLD(bC, (t + 2 < T) ? t + 2 : T - 1);
        step(t, bA);
        PLD(bD, (t + 3 < T) ? t + 3 : T - 1);
        step(t + 1, bB);
        PLD(bA, (t + 4 < T) ? t + 4 : T - 1);
        step(t + 2, bC);
        PLD(bB, (t + 5 < T) ? t + 5 : T - 1);
        step(t + 3, bD);
    }
#undef PLD
    hstate[(size_t)(bbase + row) * 256 + cb + colq]      = hm0;
    hstate[(size_t)(bbase + row) * 256 + cb + 16 + colq] = hm1;
}

// ---------------------------------------------------------------------------
// Mega pipeline tick: blocks 0-31 rec0(chunk k), 32-63 rec1(chunk k-2),
// 64..64+NGB-1 grid-stride over gemm0(chunk k+1) + gemm1(chunk k-1) tiles.
// flags: bit0 rec0, bit1 gemm1, bit2 rec1, bit3 gemm0.
// ---------------------------------------------------------------------------
__global__ __launch_bounds__(512) void mega(
    const bf16* __restrict__ xa, int t0n,
    const bf16* __restrict__ W0, const float* __restrict__ b0,
    const bf16* __restrict__ W1, const float* __restrict__ b1,
    const bf16* __restrict__ U0, const bf16* __restrict__ U1,
    float* __restrict__ h0s, float* __restrict__ h1s,
    float* __restrict__ pre0n,        // gemm0 out  (chunk k+1)
    const float* __restrict__ pre0c,  // rec0  in   (chunk k)
    bf16*  __restrict__ h1bc,         // rec0  out  (chunk k)
    const bf16* __restrict__ h1bp,    // gemm1 in   (chunk k-1)
    float* __restrict__ pre1p,        // gemm1 out  (chunk k-1)
    const float* __restrict__ pre1pp, // rec1  in   (chunk k-2)
    int flags, int T)
{
    __shared__ __align__(16) char smem[SMEM_BYTES];
    int bx = blockIdx.x;
    if (bx < 32) {
        if (flags & 1) rec_wg(smem, bx, pre0c, h1bc, U0, h0s, T);
        return;
    }
    if (bx < 64) {
        if (flags & 4) rec_wg(smem, bx - 32, pre1pp, nullptr, U1, h1s, T);
        return;
    }
    int ng0 = (flags & 8) ? T * 6 : 0;
    int ng1 = (flags & 2) ? T * 6 : 0;
    for (int tile = bx - 64; tile < ng0 + ng1; tile += NGB) {
        bool is0 = tile < ng0;
        int tt = is0 ? tile : tile - ng0;
        int t = tt / 6, nb = tt - t * 6;
        const bf16* A = is0 ? (xa + (size_t)(t0n + t) * 32768)
                            : (h1bp + (size_t)t * 32768);
        gemm_tile(smem, A, is0 ? W0 : W1, is0 ? b0 : b1,
                  is0 ? pre0n : pre1p, t, nb);
    }
}

// ---------------------------------------------------------------------------
// fc head: out[b][o] = fcb[o] + sum_h h2[b][h] * fcWT[h][o]   (all fp32)
// ---------------------------------------------------------------------------
__global__ void fc_head(const float* __restrict__ h2, const float* __restrict__ fcWT,
                        const float* __restrict__ fcb, float* __restrict__ out)
{
    int b = blockIdx.x, o = threadIdx.x;
    __shared__ float hrow[256];
    hrow[o] = h2[(size_t)b * 256 + o];
    __syncthreads();
    float acc = fcb[o];
#pragma unroll 8
    for (int h = 0; h < 256; ++h)
        acc = fmaf(hrow[h], fcWT[h * 256 + o], acc);
    out[(size_t)b * 256 + o] = acc;
}

// ---------------------------------------------------------------------------
extern "C" void kernel_launch(void* const* d_in, const int* in_sizes, int n_in,
                              void* d_out, int out_size, void* d_ws, size_t ws_size,
                              hipStream_t stream)
{
    (void)in_sizes; (void)n_in; (void)out_size;
    const float* x   = (const float*)d_in[0];
    const float* Wf0 = (const float*)d_in[1];
    const float* bf0 = (const float*)d_in[2];
    const float* Uf0 = (const float*)d_in[3];
    const float* Wi0 = (const float*)d_in[4];
    const float* bi0 = (const float*)d_in[5];
    const float* Ui0 = (const float*)d_in[6];
    const float* Wx0 = (const float*)d_in[7];
    const float* bx0 = (const float*)d_in[8];
    const float* Wf1 = (const float*)d_in[9];
    const float* bf1 = (const float*)d_in[10];
    const float* Uf1 = (const float*)d_in[11];
    const float* Wi1 = (const float*)d_in[12];
    const float* bi1 = (const float*)d_in[13];
    const float* Ui1 = (const float*)d_in[14];
    const float* Wx1 = (const float*)d_in[15];
    const float* bx1 = (const float*)d_in[16];
    const float* fcW = (const float*)d_in[17];
    const float* fcb = (const float*)d_in[18];

    char* p = (char*)d_ws;
    auto alloc = [&](size_t bytes) -> char* {
        char* r = p; p += (bytes + 255) & ~(size_t)255; return r;
    };
    bf16*  W0cat = (bf16*)alloc(768 * 256 * 2);
    bf16*  W1cat = (bf16*)alloc(768 * 256 * 2);
    bf16*  U0cat = (bf16*)alloc(512 * 256 * 2);
    bf16*  U1cat = (bf16*)alloc(512 * 256 * 2);
    float* b0cat = (float*)alloc(768 * 4);
    float* b1cat = (float*)alloc(768 * 4);
    float* fcWT  = (float*)alloc(256 * 256 * 4);
    float* h0s   = (float*)alloc(128 * 256 * 4);
    float* h1s   = (float*)alloc(128 * 256 * 4);
    size_t fixed = (size_t)(p - (char*)d_ws);

    // need(T_c) = fixed + xa(full S) + 2*pre0 + 2*pre1 + 2*h1b
    int T_c = 128;
    while (T_c > 32 &&
           fixed + 134217728ULL + (size_t)T_c * 1703936ULL + 4096 > ws_size)
        T_c >>= 1;
    bf16*  xa    = (bf16*)alloc((size_t)S_ * 128 * 256 * 2);
    float* pre0s[2], *pre1s[2];
    bf16*  h1bs[2];
    pre0s[0] = (float*)alloc((size_t)T_c * 128 * 768 * 4);
    pre0s[1] = (float*)alloc((size_t)T_c * 128 * 768 * 4);
    pre1s[0] = (float*)alloc((size_t)T_c * 128 * 768 * 4);
    pre1s[1] = (float*)alloc((size_t)T_c * 128 * 768 * 4);
    h1bs[0]  = (bf16*)alloc((size_t)T_c * 128 * 256 * 2);
    h1bs[1]  = (bf16*)alloc((size_t)T_c * 128 * 256 * 2);

    hipMemsetAsync(h0s, 0, 128 * 256 * 4, stream);
    hipMemsetAsync(h1s, 0, 128 * 256 * 4, stream);

    prep_weights<<<512, 256, 0, stream>>>(Wf0, Wi0, Wx0, Wf1, Wi1, Wx1,
                                          Uf0, Ui0, Uf1, Ui1,
                                          bf0, bi0, bx0, bf1, bi1, bx1, fcW,
                                          W0cat, W1cat, U0cat, U1cat, b0cat, b1cat, fcWT);
    convert_x<<<S_ * 32, 256, 0, stream>>>(x, xa, 0, S_);

    int NC = S_ / T_c;
    for (int k = -1; k <= NC + 1; ++k) {
        int flags = 0;
        if (k >= 0 && k < NC)     flags |= 1;   // rec0 chunk k
        if (k >= 1 && k <= NC)    flags |= 2;   // gemm1 chunk k-1
        if (k >= 2 && k <= NC+1)  flags |= 4;   // rec1 chunk k-2
        if (k <= NC - 2)          flags |= 8;   // gemm0 chunk k+1
        mega<<<64 + NGB, 512, 0, stream>>>(
            xa, (k + 1) * T_c,
            W0cat, b0cat, W1cat, b1cat, U0cat, U1cat, h0s, h1s,
            pre0s[(k + 1) & 1],   // gemm0 out
            pre0s[k & 1],         // rec0 in
            h1bs[k & 1],          // rec0 out
            h1bs[(k - 1) & 1],    // gemm1 in
            pre1s[(k - 1) & 1],   // gemm1 out
            pre1s[k & 1],         // rec1 in  ((k-2)&1 == k&1)
            flags, T_c);
    }
    fc_head<<<128, 256, 0, stream>>>(h1s, fcWT, fcb, (float*)d_out);
}